// Round 5
// baseline (311.457 us; speedup 1.0000x reference)
//
#include <hip/hip_runtime.h>
#include <hip/hip_bf16.h>

#define EMB 1024
#define SEQ 2048
#define ATT_SCALE 0.18033688011112042f  // 0.125 * log2(e)

typedef __bf16 bf16x8 __attribute__((ext_vector_type(8)));
typedef float f32x4 __attribute__((ext_vector_type(4)));
typedef float f32x16 __attribute__((ext_vector_type(16)));

__device__ __forceinline__ unsigned short f2bf(float f) {
    union { float f; unsigned int u; } v; v.f = f;
    unsigned int r = (v.u + 0x7FFFu + ((v.u >> 16) & 1u)) >> 16;
    return (unsigned short)r;
}

__device__ __forceinline__ void async_load16(const void* g, void* l) {
    __builtin_amdgcn_global_load_lds(
        (const __attribute__((address_space(1))) unsigned int*)g,
        (__attribute__((address_space(3))) unsigned int*)l, 16, 0, 0);
}

// ---------------- fp32 -> bf16 elementwise ----------------
__global__ void cvt_bf16(const float4* __restrict__ in, ushort4* __restrict__ out, int n4) {
    int i = blockIdx.x * blockDim.x + threadIdx.x;
    int stride = gridDim.x * blockDim.x;
    for (; i < n4; i += stride) {
        float4 v = in[i];
        ushort4 o;
        o.x = f2bf(v.x); o.y = f2bf(v.y); o.z = f2bf(v.z); o.w = f2bf(v.w);
        out[i] = o;
    }
}

// ---------------- transpose + convert: in [R][C] f32 -> out [C][R] bf16 ----------------
__global__ void transpose_cvt(const float* __restrict__ in, unsigned short* __restrict__ out,
                              int R, int C) {
    __shared__ float tile[32][33];
    int bx = blockIdx.x * 32;
    int by = blockIdx.y * 32;
    int tx = threadIdx.x & 31;
    int ty = threadIdx.x >> 5;
    #pragma unroll
    for (int i = 0; i < 32; i += 8)
        tile[ty + i][tx] = in[(size_t)(by + ty + i) * C + bx + tx];
    __syncthreads();
    #pragma unroll
    for (int i = 0; i < 32; i += 8)
        out[(size_t)(bx + ty + i) * R + by + tx] = f2bf(tile[tx][ty + i]);
}

// ---------------- bf16 MFMA GEMM (m97 structure): C[M,N] = A * Bt^T + bias ----------------
#define BM 128
#define BN 128
#define BK 64

template<bool OUT_BF16>
__global__ __launch_bounds__(256, 2)
void gemm_bf16(const unsigned short* __restrict__ A,
               const unsigned short* __restrict__ Bt,
               const float* __restrict__ bias,
               void* __restrict__ Cout,
               int M, int N, int K) {
    __shared__ unsigned short As[BM * 64];
    __shared__ unsigned short Bs[BN * 64];
    const int tid = threadIdx.x;
    const int m0 = blockIdx.y * BM;
    const int n0 = blockIdx.x * BN;
    const int lane = tid & 63;
    const int wave = tid >> 6;
    const int wm = (wave & 1) * 64;
    const int wn = (wave >> 1) * 64;
    const int lm = lane & 15;
    const int quad = lane >> 4;
    const int r8 = lane >> 3;
    const int pc = lane & 7;

    f32x4 acc[4][4] = {};

    for (int k0 = 0; k0 < K; k0 += BK) {
        __syncthreads();
        #pragma unroll
        for (int i = 0; i < 4; i++) {
            int r = wave * 32 + i * 8 + r8;
            int lc = pc ^ (r & 7);
            async_load16(&A[(size_t)(m0 + r) * K + k0 + lc * 8], &As[(wave * 32 + i * 8) * 64]);
            async_load16(&Bt[(size_t)(n0 + r) * K + k0 + lc * 8], &Bs[(wave * 32 + i * 8) * 64]);
        }
        __syncthreads();
        #pragma unroll
        for (int kk = 0; kk < 2; kk++) {
            bf16x8 af[4], bfr[4];
            #pragma unroll
            for (int t = 0; t < 4; t++) {
                int phys = ((kk * 4 + quad) ^ (lm & 7)) << 3;
                af[t]  = *(const bf16x8*)&As[(wm + t * 16 + lm) * 64 + phys];
                bfr[t] = *(const bf16x8*)&Bs[(wn + t * 16 + lm) * 64 + phys];
            }
            #pragma unroll
            for (int mt = 0; mt < 4; mt++)
                #pragma unroll
                for (int nt = 0; nt < 4; nt++)
                    acc[mt][nt] = __builtin_amdgcn_mfma_f32_16x16x32_bf16(
                        af[mt], bfr[nt], acc[mt][nt], 0, 0, 0);
        }
    }
    #pragma unroll
    for (int mt = 0; mt < 4; mt++) {
        #pragma unroll
        for (int nt = 0; nt < 4; nt++) {
            int col = n0 + wn + nt * 16 + lm;
            float bv = bias[col];
            #pragma unroll
            for (int r = 0; r < 4; r++) {
                int row = m0 + wm + mt * 16 + quad * 4 + r;
                float val = acc[mt][nt][r] + bv;
                if (OUT_BF16)
                    ((unsigned short*)Cout)[(size_t)row * N + col] = f2bf(val);
                else
                    ((float*)Cout)[(size_t)row * N + col] = val;
            }
        }
    }
}

// ---------------- V transpose: qkv bf16 [8192][3072] V-part -> Vt [B*H][64 d][2048 s] ----------------
__global__ void transpose_v(const unsigned short* __restrict__ qkv,
                            unsigned short* __restrict__ vt) {
    __shared__ unsigned short T[64 * 72];
    const int tid = threadIdx.x;
    const int sb = blockIdx.x;
    const int bh = blockIdx.y;
    const int b = bh >> 4;
    const int h = bh & 15;
    const unsigned short* src = qkv + (size_t)(b * SEQ + sb * 64) * 3072 + 2 * EMB + h * 64;
    #pragma unroll
    for (int i = 0; i < 2; i++) {
        int c = tid + 256 * i;
        int row = c >> 3;
        int col = (c & 7) * 8;
        *(uint4*)&T[row * 72 + col] = *(const uint4*)&src[(size_t)row * 3072 + col];
    }
    __syncthreads();
    unsigned short* dst = vt + (size_t)bh * 64 * SEQ + sb * 64;
    #pragma unroll
    for (int i = 0; i < 2; i++) {
        int c = tid + 256 * i;
        int dr = c >> 3;
        int sc = (c & 7) * 8;
        unsigned short tmp[8];
        #pragma unroll
        for (int j = 0; j < 8; j++) tmp[j] = T[(sc + j) * 72 + dr];
        *(uint4*)&dst[(size_t)dr * SEQ + sc] = *(uint4*)tmp;
    }
}

// ---------------- MFMA flash attention, S^T formulation, double-buffered ----------------
// grid (64 bh, 8 pair): co-bh blocks have ids == bh (mod 8) -> same XCD -> K/V L2 reuse.
// Block does qt = pair then 15-pair (equal work). 4 waves x 32 q-rows.
// LDS double buffer (2x(K,V) tiles): ONE barrier per k-iter.
__global__ __launch_bounds__(256, 2)
void attention(const unsigned short* __restrict__ qkv,   // [8192][3072] bf16
               const unsigned short* __restrict__ vt,    // [64][64][2048] bf16
               unsigned short* __restrict__ outb) {      // [8192][1024] bf16
    __shared__ unsigned short smem[4 * 64 * 72];         // Ks0|Vs0|Ks1|Vs1; epilogue reuses [0..128*72)
    const int tid = threadIdx.x;
    const int lane = tid & 63;
    const int wave = tid >> 6;
    const int l31 = lane & 31;
    const int half = lane >> 5;
    const int bh = blockIdx.x;
    const int b = bh >> 4;
    const int h = bh & 15;
    const int srow0 = tid >> 3;
    const int sch  = (tid & 7) * 8;

    for (int ph = 0; ph < 2; ph++) {
        const int qt = ph ? (15 - (int)blockIdx.y) : (int)blockIdx.y;
        const int qs = qt * 128 + wave * 32 + l31;
        const size_t qgrow = (size_t)b * SEQ + qs;

        bf16x8 qf[4];
        #pragma unroll
        for (int dt = 0; dt < 4; dt++)
            qf[dt] = *(const bf16x8*)&qkv[qgrow * 3072 + h * 64 + dt * 16 + half * 8];

        f32x16 o[2] = {};
        float m_prev = -1e30f, lsum = 0.f;

        const int nkb = 2 * qt + 2;
        const int qmax_w = qt * 128 + wave * 32 + 31;

        uint4 kreg[2], vreg[2];
        #pragma unroll
        for (int i = 0; i < 2; i++) {
            int row = srow0 + 32 * i;
            kreg[i] = *(const uint4*)&qkv[(size_t)(b * SEQ + row) * 3072 + EMB + h * 64 + sch];
            vreg[i] = *(const uint4*)&vt[(size_t)(bh * 64 + row) * SEQ + sch];
        }

        for (int kb = 0; kb < nkb; kb++) {
            unsigned short* Ks = smem + (kb & 1) * 2 * 64 * 72;
            unsigned short* Vs = Ks + 64 * 72;
            // write staged regs into current buffer (other buffer still being read last iter? no:
            // buffer cur was last read at iter kb-2, all readers passed barrier kb-1 before this write)
            #pragma unroll
            for (int i = 0; i < 2; i++) {
                int row = srow0 + 32 * i;
                *(uint4*)&Ks[row * 72 + sch] = kreg[i];
                *(uint4*)&Vs[row * 72 + sch] = vreg[i];
            }
            // prefetch next tile into regs (overlaps everything below)
            if (kb + 1 < nkb) {
                #pragma unroll
                for (int i = 0; i < 2; i++) {
                    int row = srow0 + 32 * i;
                    kreg[i] = *(const uint4*)&qkv[(size_t)(b * SEQ + (kb + 1) * 64 + row) * 3072 + EMB + h * 64 + sch];
                    vreg[i] = *(const uint4*)&vt[(size_t)(bh * 64 + row) * SEQ + (kb + 1) * 64 + sch];
                }
            }
            __syncthreads();   // single barrier per iter: staging of cur visible to all

            if (kb * 64 > qmax_w) continue;   // fully masked for this wave

            // S^T = K Q^T : 2 c-tiles x 32 q
            f32x16 st[2] = {};
            #pragma unroll
            for (int dt = 0; dt < 4; dt++) {
                #pragma unroll
                for (int ct = 0; ct < 2; ct++) {
                    bf16x8 kf = *(const bf16x8*)&Ks[(ct * 32 + l31) * 72 + dt * 16 + half * 8];
                    st[ct] = __builtin_amdgcn_mfma_f32_32x32x16_bf16(kf, qf[dt], st[ct], 0, 0, 0);
                }
            }

            if (kb * 64 + 63 > qt * 128 + wave * 32) {
                #pragma unroll
                for (int ct = 0; ct < 2; ct++)
                    #pragma unroll
                    for (int r = 0; r < 16; r++) {
                        int cg = kb * 64 + ct * 32 + (r & 3) + 8 * (r >> 2) + 4 * half;
                        if (cg > qs) st[ct][r] = -1e9f;
                    }
            }

            // online softmax: tree reductions (depth 4) + one cross-half shfl
            float tm[8];
            #pragma unroll
            for (int r = 0; r < 8; r++)
                tm[r] = fmaxf(fmaxf(st[0][r], st[1][r]), fmaxf(st[0][r + 8], st[1][r + 8]));
            #pragma unroll
            for (int s = 4; s > 0; s >>= 1)
                #pragma unroll
                for (int r = 0; r < s; r++) tm[r] = fmaxf(tm[r], tm[r + s]);
            float mx = fmaxf(tm[0], __shfl_xor(tm[0], 32, 64));
            float m_new = fmaxf(m_prev, mx);
            float alpha = exp2f((m_prev - m_new) * ATT_SCALE);
            float nmc = -m_new * ATT_SCALE;
            #pragma unroll
            for (int r = 0; r < 16; r++) {
                st[0][r] = exp2f(__builtin_fmaf(st[0][r], ATT_SCALE, nmc));
                st[1][r] = exp2f(__builtin_fmaf(st[1][r], ATT_SCALE, nmc));
            }
            float ts[8];
            #pragma unroll
            for (int r = 0; r < 8; r++)
                ts[r] = (st[0][r] + st[1][r]) + (st[0][r + 8] + st[1][r + 8]);
            #pragma unroll
            for (int s = 4; s > 0; s >>= 1)
                #pragma unroll
                for (int r = 0; r < s; r++) ts[r] += ts[r + s];
            float sum = ts[0] + __shfl_xor(ts[0], 32, 64);
            lsum = lsum * alpha + sum;
            m_prev = m_new;
            #pragma unroll
            for (int r = 0; r < 16; r++) { o[0][r] *= alpha; o[1][r] *= alpha; }

            // pack P to bf16 pairs
            unsigned int pk[2][8];
            #pragma unroll
            for (int t = 0; t < 2; t++)
                #pragma unroll
                for (int i = 0; i < 8; i++) {
                    __hip_bfloat162 pb = __float22bfloat162_rn(float2{st[t][2 * i], st[t][2 * i + 1]});
                    union { __hip_bfloat162 b; unsigned int u; } cv; cv.b = pb;
                    pk[t][i] = cv.u;
                }

            // P^T B-frags via half-wave exchange; O^T += V^T P^T
            #pragma unroll
            for (int kt = 0; kt < 4; kt++) {
                const int t = kt >> 1, e = kt & 1;
                unsigned int own0 = half ? pk[t][4 * e + 2] : pk[t][4 * e + 0];
                unsigned int own1 = half ? pk[t][4 * e + 3] : pk[t][4 * e + 1];
                unsigned int snd0 = half ? pk[t][4 * e + 0] : pk[t][4 * e + 2];
                unsigned int snd1 = half ? pk[t][4 * e + 1] : pk[t][4 * e + 3];
                unsigned int rcv0 = (unsigned int)__shfl_xor((int)snd0, 32, 64);
                unsigned int rcv1 = (unsigned int)__shfl_xor((int)snd1, 32, 64);
                union { uint4 u; bf16x8 v; } pf;
                pf.u.x = half ? rcv0 : own0;
                pf.u.y = half ? rcv1 : own1;
                pf.u.z = half ? own0 : rcv0;
                pf.u.w = half ? own1 : rcv1;
                #pragma unroll
                for (int dt = 0; dt < 2; dt++) {
                    bf16x8 vf = *(const bf16x8*)&Vs[(dt * 32 + l31) * 72 + kt * 16 + half * 8];
                    o[dt] = __builtin_amdgcn_mfma_f32_32x32x16_bf16(vf, pf.v, o[dt], 0, 0, 0);
                }
            }
        }

        // epilogue: O^T -> LDS [q][d] -> coalesced bf16 store
        __syncthreads();
        float inv = 1.0f / lsum;
        #pragma unroll
        for (int dt = 0; dt < 2; dt++)
            #pragma unroll
            for (int r = 0; r < 16; r++) {
                int d = dt * 32 + (r & 3) + 8 * (r >> 2) + 4 * half;
                smem[(wave * 32 + l31) * 72 + d] = f2bf(o[dt][r] * inv);
            }
        __syncthreads();
        #pragma unroll
        for (int i = 0; i < 4; i++) {
            int c = tid + 256 * i;
            int row = c >> 3;
            int ch = (c & 7) * 8;
            uint4 v = *(const uint4*)&smem[row * 72 + ch];
            *(uint4*)&outb[(size_t)(b * SEQ + qt * 128 + row) * EMB + h * 64 + ch] = v;
        }
        __syncthreads();   // protect smem before next phase's staging writes
    }
}

extern "C" void kernel_launch(void* const* d_in, const int* in_sizes, int n_in,
                              void* d_out, int out_size, void* d_ws, size_t ws_size,
                              hipStream_t stream) {
    const float* X     = (const float*)d_in[0];
    const float* Wqkv  = (const float*)d_in[1];
    const float* bqkv  = (const float*)d_in[2];
    const float* Wproj = (const float*)d_in[3];
    const float* bproj = (const float*)d_in[4];
    float* out = (float*)d_out;

    char* ws = (char*)d_ws;
    unsigned short* Xb     = (unsigned short*)(ws);                // 16,777,216 B
    unsigned short* WqkvT  = (unsigned short*)(ws + 16777216);     //  6,291,456 B
    unsigned short* WprojT = (unsigned short*)(ws + 23068672);     //  2,097,152 B
    unsigned short* qkvb   = (unsigned short*)(ws + 25165824);     // 50,331,648 B
    unsigned short* Vt     = (unsigned short*)(ws + 75497472);     // 16,777,216 B
    unsigned short* attnb  = (unsigned short*)(ws + 92274688);     // 16,777,216 B

    cvt_bf16<<<2048, 256, 0, stream>>>((const float4*)X, (ushort4*)Xb, (4 * 2048 * 1024) / 4);
    transpose_cvt<<<dim3(3072 / 32, 1024 / 32), 256, 0, stream>>>(Wqkv, WqkvT, 1024, 3072);
    transpose_cvt<<<dim3(1024 / 32, 1024 / 32), 256, 0, stream>>>(Wproj, WprojT, 1024, 1024);
    gemm_bf16<true><<<dim3(3072 / BN, 8192 / BM), 256, 0, stream>>>(
        Xb, WqkvT, bqkv, qkvb, 8192, 3072, 1024);
    transpose_v<<<dim3(32, 64), 256, 0, stream>>>(qkvb, Vt);
    attention<<<dim3(64, 8), 256, 0, stream>>>(qkvb, Vt, attnb);
    gemm_bf16<false><<<dim3(1024 / BN, 8192 / BM), 256, 0, stream>>>(
        attnb, WprojT, bproj, out, 8192, 1024, 1024);
}

// Round 6
// 303.845 us; speedup vs baseline: 1.0251x; 1.0251x over previous
//
#include <hip/hip_runtime.h>
#include <hip/hip_bf16.h>

#define EMB 1024
#define SEQ 2048
#define ATT_SCALE 0.18033688011112042f  // 0.125 * log2(e)

typedef __bf16 bf16x8 __attribute__((ext_vector_type(8)));
typedef float f32x4 __attribute__((ext_vector_type(4)));
typedef float f32x16 __attribute__((ext_vector_type(16)));

__device__ __forceinline__ unsigned short f2bf(float f) {
    union { float f; unsigned int u; } v; v.f = f;
    unsigned int r = (v.u + 0x7FFFu + ((v.u >> 16) & 1u)) >> 16;
    return (unsigned short)r;
}

__device__ __forceinline__ void async_load16(const void* g, void* l) {
    __builtin_amdgcn_global_load_lds(
        (const __attribute__((address_space(1))) unsigned int*)g,
        (__attribute__((address_space(3))) unsigned int*)l, 16, 0, 0);
}

// ---------------- fp32 -> bf16 elementwise ----------------
__global__ void cvt_bf16(const float4* __restrict__ in, ushort4* __restrict__ out, int n4) {
    int i = blockIdx.x * blockDim.x + threadIdx.x;
    int stride = gridDim.x * blockDim.x;
    for (; i < n4; i += stride) {
        float4 v = in[i];
        ushort4 o;
        o.x = f2bf(v.x); o.y = f2bf(v.y); o.z = f2bf(v.z); o.w = f2bf(v.w);
        out[i] = o;
    }
}

// ---------------- transpose + convert: in [R][C] f32 -> out [C][R] bf16 ----------------
__global__ void transpose_cvt(const float* __restrict__ in, unsigned short* __restrict__ out,
                              int R, int C) {
    __shared__ float tile[32][33];
    int bx = blockIdx.x * 32;
    int by = blockIdx.y * 32;
    int tx = threadIdx.x & 31;
    int ty = threadIdx.x >> 5;
    #pragma unroll
    for (int i = 0; i < 32; i += 8)
        tile[ty + i][tx] = in[(size_t)(by + ty + i) * C + bx + tx];
    __syncthreads();
    #pragma unroll
    for (int i = 0; i < 32; i += 8)
        out[(size_t)(bx + ty + i) * R + by + tx] = f2bf(tile[tx][ty + i]);
}

// ---------------- bf16 MFMA GEMM (m97 structure): C[M,N] = A * Bt^T + bias ----------------
#define BM 128
#define BN 128
#define BK 64

template<bool OUT_BF16>
__global__ __launch_bounds__(256, 2)
void gemm_bf16(const unsigned short* __restrict__ A,
               const unsigned short* __restrict__ Bt,
               const float* __restrict__ bias,
               void* __restrict__ Cout,
               int M, int N, int K) {
    __shared__ unsigned short As[BM * 64];
    __shared__ unsigned short Bs[BN * 64];
    const int tid = threadIdx.x;
    const int m0 = blockIdx.y * BM;
    const int n0 = blockIdx.x * BN;
    const int lane = tid & 63;
    const int wave = tid >> 6;
    const int wm = (wave & 1) * 64;
    const int wn = (wave >> 1) * 64;
    const int lm = lane & 15;
    const int quad = lane >> 4;
    const int r8 = lane >> 3;
    const int pc = lane & 7;

    f32x4 acc[4][4] = {};

    for (int k0 = 0; k0 < K; k0 += BK) {
        __syncthreads();
        #pragma unroll
        for (int i = 0; i < 4; i++) {
            int r = wave * 32 + i * 8 + r8;
            int lc = pc ^ (r & 7);
            async_load16(&A[(size_t)(m0 + r) * K + k0 + lc * 8], &As[(wave * 32 + i * 8) * 64]);
            async_load16(&Bt[(size_t)(n0 + r) * K + k0 + lc * 8], &Bs[(wave * 32 + i * 8) * 64]);
        }
        __syncthreads();
        #pragma unroll
        for (int kk = 0; kk < 2; kk++) {
            bf16x8 af[4], bfr[4];
            #pragma unroll
            for (int t = 0; t < 4; t++) {
                int phys = ((kk * 4 + quad) ^ (lm & 7)) << 3;
                af[t]  = *(const bf16x8*)&As[(wm + t * 16 + lm) * 64 + phys];
                bfr[t] = *(const bf16x8*)&Bs[(wn + t * 16 + lm) * 64 + phys];
            }
            #pragma unroll
            for (int mt = 0; mt < 4; mt++)
                #pragma unroll
                for (int nt = 0; nt < 4; nt++)
                    acc[mt][nt] = __builtin_amdgcn_mfma_f32_16x16x32_bf16(
                        af[mt], bfr[nt], acc[mt][nt], 0, 0, 0);
        }
    }
    #pragma unroll
    for (int mt = 0; mt < 4; mt++) {
        #pragma unroll
        for (int nt = 0; nt < 4; nt++) {
            int col = n0 + wn + nt * 16 + lm;
            float bv = bias[col];
            #pragma unroll
            for (int r = 0; r < 4; r++) {
                int row = m0 + wm + mt * 16 + quad * 4 + r;
                float val = acc[mt][nt][r] + bv;
                if (OUT_BF16)
                    ((unsigned short*)Cout)[(size_t)row * N + col] = f2bf(val);
                else
                    ((float*)Cout)[(size_t)row * N + col] = val;
            }
        }
    }
}

// ---------------- V transpose: qkv bf16 [8192][3072] V-part -> Vt [B*H][64 d][2048 s] ----------------
__global__ void transpose_v(const unsigned short* __restrict__ qkv,
                            unsigned short* __restrict__ vt) {
    __shared__ unsigned short T[64 * 72];
    const int tid = threadIdx.x;
    const int sb = blockIdx.x;
    const int bh = blockIdx.y;
    const int b = bh >> 4;
    const int h = bh & 15;
    const unsigned short* src = qkv + (size_t)(b * SEQ + sb * 64) * 3072 + 2 * EMB + h * 64;
    #pragma unroll
    for (int i = 0; i < 2; i++) {
        int c = tid + 256 * i;
        int row = c >> 3;
        int col = (c & 7) * 8;
        *(uint4*)&T[row * 72 + col] = *(const uint4*)&src[(size_t)row * 3072 + col];
    }
    __syncthreads();
    unsigned short* dst = vt + (size_t)bh * 64 * SEQ + sb * 64;
    #pragma unroll
    for (int i = 0; i < 2; i++) {
        int c = tid + 256 * i;
        int dr = c >> 3;
        int sc = (c & 7) * 8;
        unsigned short tmp[8];
        #pragma unroll
        for (int j = 0; j < 8; j++) tmp[j] = T[(sc + j) * 72 + dr];
        *(uint4*)&dst[(size_t)dr * SEQ + sc] = *(uint4*)tmp;
    }
}

// ---------------- MFMA flash attention, S^T formulation, double-buffered ----------------
// grid (64 bh, 16 qt): 1024 blocks -> 4 blocks/CU resident (LDS 36 KB, VGPR<=128).
// qt = 15 - blockIdx.y: longest blocks dispatch first (LPT) -> minimal makespan tail.
// Co-bh blocks have ids == bh (mod 8) -> same XCD -> K/V L2 reuse.
// 4 waves x 32 q-rows. LDS double buffer: ONE barrier per k-iter.
__global__ __launch_bounds__(256, 4)
void attention(const unsigned short* __restrict__ qkv,   // [8192][3072] bf16
               const unsigned short* __restrict__ vt,    // [64][64][2048] bf16
               unsigned short* __restrict__ outb) {      // [8192][1024] bf16
    __shared__ unsigned short smem[4 * 64 * 72];         // Ks0|Vs0|Ks1|Vs1; epilogue reuses [0..128*72)
    const int tid = threadIdx.x;
    const int lane = tid & 63;
    const int wave = tid >> 6;
    const int l31 = lane & 31;
    const int half = lane >> 5;
    const int bh = blockIdx.x;
    const int b = bh >> 4;
    const int h = bh & 15;
    const int srow0 = tid >> 3;
    const int sch  = (tid & 7) * 8;

    const int qt = 15 - (int)blockIdx.y;
    const int qs = qt * 128 + wave * 32 + l31;
    const size_t qgrow = (size_t)b * SEQ + qs;

    bf16x8 qf[4];
    #pragma unroll
    for (int dt = 0; dt < 4; dt++)
        qf[dt] = *(const bf16x8*)&qkv[qgrow * 3072 + h * 64 + dt * 16 + half * 8];

    f32x16 o[2] = {};
    float m_prev = -1e30f, lsum = 0.f;

    const int nkb = 2 * qt + 2;
    const int qmax_w = qt * 128 + wave * 32 + 31;

    uint4 kreg[2], vreg[2];
    #pragma unroll
    for (int i = 0; i < 2; i++) {
        int row = srow0 + 32 * i;
        kreg[i] = *(const uint4*)&qkv[(size_t)(b * SEQ + row) * 3072 + EMB + h * 64 + sch];
        vreg[i] = *(const uint4*)&vt[(size_t)(bh * 64 + row) * SEQ + sch];
    }

    for (int kb = 0; kb < nkb; kb++) {
        unsigned short* Ks = smem + (kb & 1) * 2 * 64 * 72;
        unsigned short* Vs = Ks + 64 * 72;
        // write staged regs (buffer cur was last read at iter kb-2; all readers passed barrier kb-1)
        #pragma unroll
        for (int i = 0; i < 2; i++) {
            int row = srow0 + 32 * i;
            *(uint4*)&Ks[row * 72 + sch] = kreg[i];
            *(uint4*)&Vs[row * 72 + sch] = vreg[i];
        }
        // prefetch next tile into regs (overlaps compute below)
        if (kb + 1 < nkb) {
            #pragma unroll
            for (int i = 0; i < 2; i++) {
                int row = srow0 + 32 * i;
                kreg[i] = *(const uint4*)&qkv[(size_t)(b * SEQ + (kb + 1) * 64 + row) * 3072 + EMB + h * 64 + sch];
                vreg[i] = *(const uint4*)&vt[(size_t)(bh * 64 + row) * SEQ + (kb + 1) * 64 + sch];
            }
        }
        __syncthreads();   // single barrier per iter

        if (kb * 64 > qmax_w) continue;   // fully masked for this wave

        // S^T = K Q^T : 2 c-tiles x 32 q
        f32x16 st[2] = {};
        #pragma unroll
        for (int dt = 0; dt < 4; dt++) {
            #pragma unroll
            for (int ct = 0; ct < 2; ct++) {
                bf16x8 kf = *(const bf16x8*)&Ks[(ct * 32 + l31) * 72 + dt * 16 + half * 8];
                st[ct] = __builtin_amdgcn_mfma_f32_32x32x16_bf16(kf, qf[dt], st[ct], 0, 0, 0);
            }
        }

        if (kb * 64 + 63 > qt * 128 + wave * 32) {
            #pragma unroll
            for (int ct = 0; ct < 2; ct++)
                #pragma unroll
                for (int r = 0; r < 16; r++) {
                    int cg = kb * 64 + ct * 32 + (r & 3) + 8 * (r >> 2) + 4 * half;
                    if (cg > qs) st[ct][r] = -1e9f;
                }
        }

        // online softmax: tree reductions + one cross-half shfl
        float tm[8];
        #pragma unroll
        for (int r = 0; r < 8; r++)
            tm[r] = fmaxf(fmaxf(st[0][r], st[1][r]), fmaxf(st[0][r + 8], st[1][r + 8]));
        #pragma unroll
        for (int s = 4; s > 0; s >>= 1)
            #pragma unroll
            for (int r = 0; r < s; r++) tm[r] = fmaxf(tm[r], tm[r + s]);
        float mx = fmaxf(tm[0], __shfl_xor(tm[0], 32, 64));
        float m_new = fmaxf(m_prev, mx);
        float alpha = exp2f((m_prev - m_new) * ATT_SCALE);
        float nmc = -m_new * ATT_SCALE;
        #pragma unroll
        for (int r = 0; r < 16; r++) {
            st[0][r] = exp2f(__builtin_fmaf(st[0][r], ATT_SCALE, nmc));
            st[1][r] = exp2f(__builtin_fmaf(st[1][r], ATT_SCALE, nmc));
        }
        float ts[8];
        #pragma unroll
        for (int r = 0; r < 8; r++)
            ts[r] = (st[0][r] + st[1][r]) + (st[0][r + 8] + st[1][r + 8]);
        #pragma unroll
        for (int s = 4; s > 0; s >>= 1)
            #pragma unroll
            for (int r = 0; r < s; r++) ts[r] += ts[r + s];
        float sum = ts[0] + __shfl_xor(ts[0], 32, 64);
        lsum = lsum * alpha + sum;
        m_prev = m_new;
        #pragma unroll
        for (int r = 0; r < 16; r++) { o[0][r] *= alpha; o[1][r] *= alpha; }

        // pack P to bf16 pairs
        unsigned int pk[2][8];
        #pragma unroll
        for (int t = 0; t < 2; t++)
            #pragma unroll
            for (int i = 0; i < 8; i++) {
                __hip_bfloat162 pb = __float22bfloat162_rn(float2{st[t][2 * i], st[t][2 * i + 1]});
                union { __hip_bfloat162 b; unsigned int u; } cv; cv.b = pb;
                pk[t][i] = cv.u;
            }

        // P^T B-frags via half-wave exchange; O^T += V^T P^T
        #pragma unroll
        for (int kt = 0; kt < 4; kt++) {
            const int t = kt >> 1, e = kt & 1;
            unsigned int own0 = half ? pk[t][4 * e + 2] : pk[t][4 * e + 0];
            unsigned int own1 = half ? pk[t][4 * e + 3] : pk[t][4 * e + 1];
            unsigned int snd0 = half ? pk[t][4 * e + 0] : pk[t][4 * e + 2];
            unsigned int snd1 = half ? pk[t][4 * e + 1] : pk[t][4 * e + 3];
            unsigned int rcv0 = (unsigned int)__shfl_xor((int)snd0, 32, 64);
            unsigned int rcv1 = (unsigned int)__shfl_xor((int)snd1, 32, 64);
            union { uint4 u; bf16x8 v; } pf;
            pf.u.x = half ? rcv0 : own0;
            pf.u.y = half ? rcv1 : own1;
            pf.u.z = half ? own0 : rcv0;
            pf.u.w = half ? own1 : rcv1;
            #pragma unroll
            for (int dt = 0; dt < 2; dt++) {
                bf16x8 vf = *(const bf16x8*)&Vs[(dt * 32 + l31) * 72 + kt * 16 + half * 8];
                o[dt] = __builtin_amdgcn_mfma_f32_32x32x16_bf16(vf, pf.v, o[dt], 0, 0, 0);
            }
        }
    }

    // epilogue: O^T -> LDS [q][d] -> coalesced bf16 store
    __syncthreads();
    float inv = 1.0f / lsum;
    #pragma unroll
    for (int dt = 0; dt < 2; dt++)
        #pragma unroll
        for (int r = 0; r < 16; r++) {
            int d = dt * 32 + (r & 3) + 8 * (r >> 2) + 4 * half;
            smem[(wave * 32 + l31) * 72 + d] = f2bf(o[dt][r] * inv);
        }
    __syncthreads();
    #pragma unroll
    for (int i = 0; i < 4; i++) {
        int c = tid + 256 * i;
        int row = c >> 3;
        int ch = (c & 7) * 8;
        uint4 v = *(const uint4*)&smem[row * 72 + ch];
        *(uint4*)&outb[(size_t)(b * SEQ + qt * 128 + row) * EMB + h * 64 + ch] = v;
    }
}

extern "C" void kernel_launch(void* const* d_in, const int* in_sizes, int n_in,
                              void* d_out, int out_size, void* d_ws, size_t ws_size,
                              hipStream_t stream) {
    const float* X     = (const float*)d_in[0];
    const float* Wqkv  = (const float*)d_in[1];
    const float* bqkv  = (const float*)d_in[2];
    const float* Wproj = (const float*)d_in[3];
    const float* bproj = (const float*)d_in[4];
    float* out = (float*)d_out;

    char* ws = (char*)d_ws;
    unsigned short* Xb     = (unsigned short*)(ws);                // 16,777,216 B
    unsigned short* WqkvT  = (unsigned short*)(ws + 16777216);     //  6,291,456 B
    unsigned short* WprojT = (unsigned short*)(ws + 23068672);     //  2,097,152 B
    unsigned short* qkvb   = (unsigned short*)(ws + 25165824);     // 50,331,648 B
    unsigned short* Vt     = (unsigned short*)(ws + 75497472);     // 16,777,216 B
    unsigned short* attnb  = (unsigned short*)(ws + 92274688);     // 16,777,216 B

    cvt_bf16<<<2048, 256, 0, stream>>>((const float4*)X, (ushort4*)Xb, (4 * 2048 * 1024) / 4);
    transpose_cvt<<<dim3(3072 / 32, 1024 / 32), 256, 0, stream>>>(Wqkv, WqkvT, 1024, 3072);
    transpose_cvt<<<dim3(1024 / 32, 1024 / 32), 256, 0, stream>>>(Wproj, WprojT, 1024, 1024);
    gemm_bf16<true><<<dim3(3072 / BN, 8192 / BM), 256, 0, stream>>>(
        Xb, WqkvT, bqkv, qkvb, 8192, 3072, 1024);
    transpose_v<<<dim3(32, 64), 256, 0, stream>>>(qkvb, Vt);
    attention<<<dim3(64, 16), 256, 0, stream>>>(qkvb, Vt, attnb);
    gemm_bf16<false><<<dim3(1024 / BN, 8192 / BM), 256, 0, stream>>>(
        attnb, WprojT, bproj, out, 8192, 1024, 1024);
}

// Round 7
// 301.292 us; speedup vs baseline: 1.0337x; 1.0085x over previous
//
#include <hip/hip_runtime.h>
#include <hip/hip_bf16.h>

#define EMB 1024
#define SEQ 2048
#define ATT_SCALE 0.18033688011112042f  // 0.125 * log2(e)

typedef __bf16 bf16x8 __attribute__((ext_vector_type(8)));
typedef float f32x4 __attribute__((ext_vector_type(4)));
typedef float f32x16 __attribute__((ext_vector_type(16)));

__device__ __forceinline__ unsigned short f2bf(float f) {
    union { float f; unsigned int u; } v; v.f = f;
    unsigned int r = (v.u + 0x7FFFu + ((v.u >> 16) & 1u)) >> 16;
    return (unsigned short)r;
}

__device__ __forceinline__ void async_load16(const void* g, void* l) {
    __builtin_amdgcn_global_load_lds(
        (const __attribute__((address_space(1))) unsigned int*)g,
        (__attribute__((address_space(3))) unsigned int*)l, 16, 0, 0);
}

// ---------------- fp32 -> bf16 elementwise ----------------
__global__ void cvt_bf16(const float4* __restrict__ in, ushort4* __restrict__ out, int n4) {
    int i = blockIdx.x * blockDim.x + threadIdx.x;
    int stride = gridDim.x * blockDim.x;
    for (; i < n4; i += stride) {
        float4 v = in[i];
        ushort4 o;
        o.x = f2bf(v.x); o.y = f2bf(v.y); o.z = f2bf(v.z); o.w = f2bf(v.w);
        out[i] = o;
    }
}

// ---------------- transpose + convert: in [R][C] f32 -> out [C][R] bf16 ----------------
__global__ void transpose_cvt(const float* __restrict__ in, unsigned short* __restrict__ out,
                              int R, int C) {
    __shared__ float tile[32][33];
    int bx = blockIdx.x * 32;
    int by = blockIdx.y * 32;
    int tx = threadIdx.x & 31;
    int ty = threadIdx.x >> 5;
    #pragma unroll
    for (int i = 0; i < 32; i += 8)
        tile[ty + i][tx] = in[(size_t)(by + ty + i) * C + bx + tx];
    __syncthreads();
    #pragma unroll
    for (int i = 0; i < 32; i += 8)
        out[(size_t)(bx + ty + i) * R + by + tx] = f2bf(tile[tx][ty + i]);
}

// ---------------- bf16 MFMA GEMM (m97 structure): C[M,N] = A * Bt^T + bias ----------------
// 1-D grid, XCD-aware swizzle: xcd = id&7 owns contiguous n-stripe (W panel stays in
// that XCD's L2: gemm1 786 KB, gemm2 256 KB). FUSE_VT: cols >= 2048 are V -> write
// transposed directly to Vt[bh][d][s] (r=0..3 = consecutive s = contiguous 8B store).
#define BM 128
#define BN 128
#define BK 64

template<bool OUT_BF16, bool FUSE_VT>
__global__ __launch_bounds__(256, 2)
void gemm_bf16(const unsigned short* __restrict__ A,
               const unsigned short* __restrict__ Bt,
               const float* __restrict__ bias,
               void* __restrict__ Cout,
               unsigned short* __restrict__ Vtout,
               int M, int N, int K) {
    __shared__ unsigned short As[BM * 64];
    __shared__ unsigned short Bs[BN * 64];
    const int tid = threadIdx.x;
    // XCD swizzle
    const int id = blockIdx.x;
    const int nb = N >> 7;
    const int nper = nb >> 3;
    const int xcd = id & 7;
    const int loc = id >> 3;
    const int m0 = (loc / nper) * BM;
    const int n0 = (xcd * nper + (loc % nper)) * BN;
    const int lane = tid & 63;
    const int wave = tid >> 6;
    const int wm = (wave & 1) * 64;
    const int wn = (wave >> 1) * 64;
    const int lm = lane & 15;
    const int quad = lane >> 4;
    const int r8 = lane >> 3;
    const int pc = lane & 7;

    f32x4 acc[4][4] = {};

    for (int k0 = 0; k0 < K; k0 += BK) {
        __syncthreads();
        #pragma unroll
        for (int i = 0; i < 4; i++) {
            int r = wave * 32 + i * 8 + r8;
            int lc = pc ^ (r & 7);
            async_load16(&A[(size_t)(m0 + r) * K + k0 + lc * 8], &As[(wave * 32 + i * 8) * 64]);
            async_load16(&Bt[(size_t)(n0 + r) * K + k0 + lc * 8], &Bs[(wave * 32 + i * 8) * 64]);
        }
        __syncthreads();
        #pragma unroll
        for (int kk = 0; kk < 2; kk++) {
            bf16x8 af[4], bfr[4];
            #pragma unroll
            for (int t = 0; t < 4; t++) {
                int phys = ((kk * 4 + quad) ^ (lm & 7)) << 3;
                af[t]  = *(const bf16x8*)&As[(wm + t * 16 + lm) * 64 + phys];
                bfr[t] = *(const bf16x8*)&Bs[(wn + t * 16 + lm) * 64 + phys];
            }
            #pragma unroll
            for (int mt = 0; mt < 4; mt++)
                #pragma unroll
                for (int nt = 0; nt < 4; nt++)
                    acc[mt][nt] = __builtin_amdgcn_mfma_f32_16x16x32_bf16(
                        af[mt], bfr[nt], acc[mt][nt], 0, 0, 0);
        }
    }
    #pragma unroll
    for (int mt = 0; mt < 4; mt++) {
        #pragma unroll
        for (int nt = 0; nt < 4; nt++) {
            int col = n0 + wn + nt * 16 + lm;
            float bv = bias[col];
            if (FUSE_VT && col >= 2 * EMB) {
                // V region: write transposed to Vt[(b*16+h)*64+d][s]
                int dd = col - 2 * EMB;           // 0..1023
                int row0 = m0 + wm + mt * 16 + quad * 4;   // 4 consecutive s
                int b = row0 >> 11;
                int s = row0 & 2047;
                ushort4 o;
                o.x = f2bf(acc[mt][nt][0] + bv);
                o.y = f2bf(acc[mt][nt][1] + bv);
                o.z = f2bf(acc[mt][nt][2] + bv);
                o.w = f2bf(acc[mt][nt][3] + bv);
                *(ushort4*)&Vtout[((size_t)(b * 16) * 64 + dd) * SEQ + s] = o;
            } else {
                #pragma unroll
                for (int r = 0; r < 4; r++) {
                    int row = m0 + wm + mt * 16 + quad * 4 + r;
                    float val = acc[mt][nt][r] + bv;
                    if (OUT_BF16)
                        ((unsigned short*)Cout)[(size_t)row * N + col] = f2bf(val);
                    else
                        ((float*)Cout)[(size_t)row * N + col] = val;
                }
            }
        }
    }
}

// ---------------- MFMA flash attention, S^T formulation, double-buffered ----------------
// grid (64 bh, 16 qt): 1024 blocks -> 4 blocks/CU resident (LDS 36 KB).
// qt = 15 - blockIdx.y: longest blocks first (LPT). Co-bh blocks share XCD (ids == bh mod 8).
// 4 waves x 32 q-rows. LDS double buffer: ONE barrier per k-iter.
__global__ __launch_bounds__(256, 4)
void attention(const unsigned short* __restrict__ qkv,   // [8192][3072] bf16
               const unsigned short* __restrict__ vt,    // [64][64][2048] bf16
               unsigned short* __restrict__ outb) {      // [8192][1024] bf16
    __shared__ unsigned short smem[4 * 64 * 72];
    const int tid = threadIdx.x;
    const int lane = tid & 63;
    const int wave = tid >> 6;
    const int l31 = lane & 31;
    const int half = lane >> 5;
    const int bh = blockIdx.x;
    const int b = bh >> 4;
    const int h = bh & 15;
    const int srow0 = tid >> 3;
    const int sch  = (tid & 7) * 8;

    const int qt = 15 - (int)blockIdx.y;
    const int qs = qt * 128 + wave * 32 + l31;
    const size_t qgrow = (size_t)b * SEQ + qs;

    bf16x8 qf[4];
    #pragma unroll
    for (int dt = 0; dt < 4; dt++)
        qf[dt] = *(const bf16x8*)&qkv[qgrow * 3072 + h * 64 + dt * 16 + half * 8];

    f32x16 o[2] = {};
    float m_prev = -1e30f, lsum = 0.f;

    const int nkb = 2 * qt + 2;
    const int qmax_w = qt * 128 + wave * 32 + 31;

    uint4 kreg[2], vreg[2];
    #pragma unroll
    for (int i = 0; i < 2; i++) {
        int row = srow0 + 32 * i;
        kreg[i] = *(const uint4*)&qkv[(size_t)(b * SEQ + row) * 3072 + EMB + h * 64 + sch];
        vreg[i] = *(const uint4*)&vt[(size_t)(bh * 64 + row) * SEQ + sch];
    }

    for (int kb = 0; kb < nkb; kb++) {
        unsigned short* Ks = smem + (kb & 1) * 2 * 64 * 72;
        unsigned short* Vs = Ks + 64 * 72;
        #pragma unroll
        for (int i = 0; i < 2; i++) {
            int row = srow0 + 32 * i;
            *(uint4*)&Ks[row * 72 + sch] = kreg[i];
            *(uint4*)&Vs[row * 72 + sch] = vreg[i];
        }
        if (kb + 1 < nkb) {
            #pragma unroll
            for (int i = 0; i < 2; i++) {
                int row = srow0 + 32 * i;
                kreg[i] = *(const uint4*)&qkv[(size_t)(b * SEQ + (kb + 1) * 64 + row) * 3072 + EMB + h * 64 + sch];
                vreg[i] = *(const uint4*)&vt[(size_t)(bh * 64 + row) * SEQ + (kb + 1) * 64 + sch];
            }
        }
        __syncthreads();

        if (kb * 64 > qmax_w) continue;

        // S^T = K Q^T : 2 c-tiles x 32 q
        f32x16 st[2] = {};
        #pragma unroll
        for (int dt = 0; dt < 4; dt++) {
            #pragma unroll
            for (int ct = 0; ct < 2; ct++) {
                bf16x8 kf = *(const bf16x8*)&Ks[(ct * 32 + l31) * 72 + dt * 16 + half * 8];
                st[ct] = __builtin_amdgcn_mfma_f32_32x32x16_bf16(kf, qf[dt], st[ct], 0, 0, 0);
            }
        }

        if (kb * 64 + 63 > qt * 128 + wave * 32) {
            #pragma unroll
            for (int ct = 0; ct < 2; ct++)
                #pragma unroll
                for (int r = 0; r < 16; r++) {
                    int cg = kb * 64 + ct * 32 + (r & 3) + 8 * (r >> 2) + 4 * half;
                    if (cg > qs) st[ct][r] = -1e9f;
                }
        }

        // online softmax: tree reductions + one cross-half shfl
        float tm[8];
        #pragma unroll
        for (int r = 0; r < 8; r++)
            tm[r] = fmaxf(fmaxf(st[0][r], st[1][r]), fmaxf(st[0][r + 8], st[1][r + 8]));
        #pragma unroll
        for (int s = 4; s > 0; s >>= 1)
            #pragma unroll
            for (int r = 0; r < s; r++) tm[r] = fmaxf(tm[r], tm[r + s]);
        float mx = fmaxf(tm[0], __shfl_xor(tm[0], 32, 64));
        float m_new = fmaxf(m_prev, mx);
        float alpha = exp2f((m_prev - m_new) * ATT_SCALE);
        float nmc = -m_new * ATT_SCALE;
        #pragma unroll
        for (int r = 0; r < 16; r++) {
            st[0][r] = exp2f(__builtin_fmaf(st[0][r], ATT_SCALE, nmc));
            st[1][r] = exp2f(__builtin_fmaf(st[1][r], ATT_SCALE, nmc));
        }
        float ts[8];
        #pragma unroll
        for (int r = 0; r < 8; r++)
            ts[r] = (st[0][r] + st[1][r]) + (st[0][r + 8] + st[1][r + 8]);
        #pragma unroll
        for (int s = 4; s > 0; s >>= 1)
            #pragma unroll
            for (int r = 0; r < s; r++) ts[r] += ts[r + s];
        float sum = ts[0] + __shfl_xor(ts[0], 32, 64);
        lsum = lsum * alpha + sum;
        m_prev = m_new;
        #pragma unroll
        for (int r = 0; r < 16; r++) { o[0][r] *= alpha; o[1][r] *= alpha; }

        // pack P to bf16 pairs
        unsigned int pk[2][8];
        #pragma unroll
        for (int t = 0; t < 2; t++)
            #pragma unroll
            for (int i = 0; i < 8; i++) {
                __hip_bfloat162 pb = __float22bfloat162_rn(float2{st[t][2 * i], st[t][2 * i + 1]});
                union { __hip_bfloat162 b; unsigned int u; } cv; cv.b = pb;
                pk[t][i] = cv.u;
            }

        // P^T B-frags via half-wave exchange; O^T += V^T P^T
        #pragma unroll
        for (int kt = 0; kt < 4; kt++) {
            const int t = kt >> 1, e = kt & 1;
            unsigned int own0 = half ? pk[t][4 * e + 2] : pk[t][4 * e + 0];
            unsigned int own1 = half ? pk[t][4 * e + 3] : pk[t][4 * e + 1];
            unsigned int snd0 = half ? pk[t][4 * e + 0] : pk[t][4 * e + 2];
            unsigned int snd1 = half ? pk[t][4 * e + 1] : pk[t][4 * e + 3];
            unsigned int rcv0 = (unsigned int)__shfl_xor((int)snd0, 32, 64);
            unsigned int rcv1 = (unsigned int)__shfl_xor((int)snd1, 32, 64);
            union { uint4 u; bf16x8 v; } pf;
            pf.u.x = half ? rcv0 : own0;
            pf.u.y = half ? rcv1 : own1;
            pf.u.z = half ? own0 : rcv0;
            pf.u.w = half ? own1 : rcv1;
            #pragma unroll
            for (int dt = 0; dt < 2; dt++) {
                bf16x8 vf = *(const bf16x8*)&Vs[(dt * 32 + l31) * 72 + kt * 16 + half * 8];
                o[dt] = __builtin_amdgcn_mfma_f32_32x32x16_bf16(vf, pf.v, o[dt], 0, 0, 0);
            }
        }
    }

    // epilogue: O^T -> LDS [q][d] -> coalesced bf16 store
    __syncthreads();
    float inv = 1.0f / lsum;
    #pragma unroll
    for (int dt = 0; dt < 2; dt++)
        #pragma unroll
        for (int r = 0; r < 16; r++) {
            int d = dt * 32 + (r & 3) + 8 * (r >> 2) + 4 * half;
            smem[(wave * 32 + l31) * 72 + d] = f2bf(o[dt][r] * inv);
        }
    __syncthreads();
    #pragma unroll
    for (int i = 0; i < 4; i++) {
        int c = tid + 256 * i;
        int row = c >> 3;
        int ch = (c & 7) * 8;
        uint4 v = *(const uint4*)&smem[row * 72 + ch];
        *(uint4*)&outb[(size_t)(b * SEQ + qt * 128 + row) * EMB + h * 64 + ch] = v;
    }
}

extern "C" void kernel_launch(void* const* d_in, const int* in_sizes, int n_in,
                              void* d_out, int out_size, void* d_ws, size_t ws_size,
                              hipStream_t stream) {
    const float* X     = (const float*)d_in[0];
    const float* Wqkv  = (const float*)d_in[1];
    const float* bqkv  = (const float*)d_in[2];
    const float* Wproj = (const float*)d_in[3];
    const float* bproj = (const float*)d_in[4];
    float* out = (float*)d_out;

    char* ws = (char*)d_ws;
    unsigned short* Xb     = (unsigned short*)(ws);                // 16,777,216 B
    unsigned short* WqkvT  = (unsigned short*)(ws + 16777216);     //  6,291,456 B
    unsigned short* WprojT = (unsigned short*)(ws + 23068672);     //  2,097,152 B
    unsigned short* qkvb   = (unsigned short*)(ws + 25165824);     // 50,331,648 B
    unsigned short* Vt     = (unsigned short*)(ws + 75497472);     // 16,777,216 B
    unsigned short* attnb  = (unsigned short*)(ws + 92274688);     // 16,777,216 B

    cvt_bf16<<<2048, 256, 0, stream>>>((const float4*)X, (ushort4*)Xb, (4 * 2048 * 1024) / 4);
    transpose_cvt<<<dim3(3072 / 32, 1024 / 32), 256, 0, stream>>>(Wqkv, WqkvT, 1024, 3072);
    transpose_cvt<<<dim3(1024 / 32, 1024 / 32), 256, 0, stream>>>(Wproj, WprojT, 1024, 1024);
    // qkv bf16 = X @ Wqkv + b ; V region written transposed to Vt
    gemm_bf16<true, true><<<(3072 / BN) * (8192 / BM), 256, 0, stream>>>(
        Xb, WqkvT, bqkv, qkvb, Vt, 8192, 3072, 1024);
    attention<<<dim3(64, 16), 256, 0, stream>>>(qkvb, Vt, attnb);
    gemm_bf16<false, false><<<(1024 / BN) * (8192 / BM), 256, 0, stream>>>(
        attnb, WprojT, bproj, out, nullptr, 8192, 1024, 1024);
}

// Round 8
// 296.607 us; speedup vs baseline: 1.0501x; 1.0158x over previous
//
#include <hip/hip_runtime.h>
#include <hip/hip_bf16.h>

#define EMB 1024
#define SEQ 2048
#define ATT_SCALE 0.18033688011112042f  // 0.125 * log2(e)

typedef __bf16 bf16x8 __attribute__((ext_vector_type(8)));
typedef float f32x4 __attribute__((ext_vector_type(4)));
typedef float f32x16 __attribute__((ext_vector_type(16)));

__device__ __forceinline__ unsigned short f2bf(float f) {
    union { float f; unsigned int u; } v; v.f = f;
    unsigned int r = (v.u + 0x7FFFu + ((v.u >> 16) & 1u)) >> 16;
    return (unsigned short)r;
}

__device__ __forceinline__ void async_load16(const void* g, void* l) {
    __builtin_amdgcn_global_load_lds(
        (const __attribute__((address_space(1))) unsigned int*)g,
        (__attribute__((address_space(3))) unsigned int*)l, 16, 0, 0);
}

// ---------------- fp32 -> bf16 elementwise ----------------
__global__ void cvt_bf16(const float4* __restrict__ in, ushort4* __restrict__ out, int n4) {
    int i = blockIdx.x * blockDim.x + threadIdx.x;
    int stride = gridDim.x * blockDim.x;
    for (; i < n4; i += stride) {
        float4 v = in[i];
        ushort4 o;
        o.x = f2bf(v.x); o.y = f2bf(v.y); o.z = f2bf(v.z); o.w = f2bf(v.w);
        out[i] = o;
    }
}

// ---------------- transpose + convert: in [R][C] f32 -> out [C][R] bf16 ----------------
__global__ void transpose_cvt(const float* __restrict__ in, unsigned short* __restrict__ out,
                              int R, int C) {
    __shared__ float tile[32][33];
    int bx = blockIdx.x * 32;
    int by = blockIdx.y * 32;
    int tx = threadIdx.x & 31;
    int ty = threadIdx.x >> 5;
    #pragma unroll
    for (int i = 0; i < 32; i += 8)
        tile[ty + i][tx] = in[(size_t)(by + ty + i) * C + bx + tx];
    __syncthreads();
    #pragma unroll
    for (int i = 0; i < 32; i += 8)
        out[(size_t)(bx + ty + i) * R + by + tx] = f2bf(tile[tx][ty + i]);
}

// ---------------- bf16 MFMA GEMM, 32x32x16 shape: C[M,N] = A * Bt^T + bias ----------------
// 1-D grid, XCD stripe: xcd = id&7 owns NPER contiguous n-blocks (W panel L2-resident).
// Wave tile 64x64 as 2x2 of 32x32. A/B frags: m(or n)=lane&31, k=half*8+j (HW-verified).
// C/D: col=lane&31, row=(reg&3)+8*(reg>>2)+4*half (HW-verified).
// FUSE_VT: cols >= 2048 are V -> write transposed to Vt[bh*64+d][s].
#define BM 128
#define BN 128
#define BK 64

template<bool OUT_BF16, bool FUSE_VT, int NPER>
__global__ __launch_bounds__(256, 2)
void gemm_bf16(const unsigned short* __restrict__ A,
               const unsigned short* __restrict__ Bt,
               const float* __restrict__ bias,
               void* __restrict__ Cout,
               unsigned short* __restrict__ Vtout,
               int M, int N, int K) {
    __shared__ unsigned short As[BM * 64];
    __shared__ unsigned short Bs[BN * 64];
    const int tid = threadIdx.x;
    const int id = blockIdx.x;
    const int xcd = id & 7;
    const int loc = id >> 3;
    const int m0 = (loc / NPER) * BM;
    const int n0 = (xcd * NPER + (loc % NPER)) * BN;
    const int lane = tid & 63;
    const int wave = tid >> 6;
    const int wm = (wave & 1) * 64;
    const int wn = (wave >> 1) * 64;
    const int l31 = lane & 31;
    const int half = lane >> 5;
    const int r8 = lane >> 3;
    const int pc = lane & 7;

    f32x16 acc[2][2] = {};

    for (int k0 = 0; k0 < K; k0 += BK) {
        __syncthreads();
        #pragma unroll
        for (int i = 0; i < 4; i++) {
            int r = wave * 32 + i * 8 + r8;
            int lc = pc ^ (r & 7);
            async_load16(&A[(size_t)(m0 + r) * K + k0 + lc * 8], &As[(wave * 32 + i * 8) * 64]);
            async_load16(&Bt[(size_t)(n0 + r) * K + k0 + lc * 8], &Bs[(wave * 32 + i * 8) * 64]);
        }
        __syncthreads();
        #pragma unroll
        for (int ks = 0; ks < 4; ks++) {   // 4 k-steps of 16
            const int lch = ks * 2 + half; // logical 16B chunk
            bf16x8 af[2], bf[2];
            #pragma unroll
            for (int t = 0; t < 2; t++) {
                int ra = wm + t * 32 + l31;
                int rb = wn + t * 32 + l31;
                af[t] = *(const bf16x8*)&As[ra * 64 + (lch ^ (ra & 7)) * 8];
                bf[t] = *(const bf16x8*)&Bs[rb * 64 + (lch ^ (rb & 7)) * 8];
            }
            #pragma unroll
            for (int mt = 0; mt < 2; mt++)
                #pragma unroll
                for (int nt = 0; nt < 2; nt++)
                    acc[mt][nt] = __builtin_amdgcn_mfma_f32_32x32x16_bf16(
                        af[mt], bf[nt], acc[mt][nt], 0, 0, 0);
        }
    }
    // epilogue: C/D col = n0+wn+nt*32+l31, row = m0+wm+mt*32 + (reg&3)+8*(reg>>2)+4*half
    #pragma unroll
    for (int mt = 0; mt < 2; mt++) {
        #pragma unroll
        for (int nt = 0; nt < 2; nt++) {
            int col = n0 + wn + nt * 32 + l31;
            float bv = bias[col];
            if (FUSE_VT && col >= 2 * EMB) {
                int dd = col - 2 * EMB;
                #pragma unroll
                for (int g = 0; g < 4; g++) {   // regs 4g..4g+3 = 4 consecutive s
                    int row0 = m0 + wm + mt * 32 + 8 * g + 4 * half;
                    int b = row0 >> 11;
                    int s = row0 & 2047;
                    ushort4 o;
                    o.x = f2bf(acc[mt][nt][4 * g + 0] + bv);
                    o.y = f2bf(acc[mt][nt][4 * g + 1] + bv);
                    o.z = f2bf(acc[mt][nt][4 * g + 2] + bv);
                    o.w = f2bf(acc[mt][nt][4 * g + 3] + bv);
                    *(ushort4*)&Vtout[((size_t)(b * 16) * 64 + dd) * SEQ + s] = o;
                }
            } else {
                #pragma unroll
                for (int reg = 0; reg < 16; reg++) {
                    int row = m0 + wm + mt * 32 + (reg & 3) + 8 * (reg >> 2) + 4 * half;
                    float val = acc[mt][nt][reg] + bv;
                    if (OUT_BF16)
                        ((unsigned short*)Cout)[(size_t)row * N + col] = f2bf(val);
                    else
                        ((float*)Cout)[(size_t)row * N + col] = val;
                }
            }
        }
    }
}

// ---------------- MFMA flash attention, S^T formulation, double-buffered ----------------
// grid (64 bh, 16 qt): 1024 blocks -> 4 blocks/CU (LDS 36 KB). qt = 15-blockIdx.y (LPT).
// Co-bh blocks share XCD (ids == bh mod 8). 4 waves x 32 q-rows. ONE barrier per k-iter.
__global__ __launch_bounds__(256, 4)
void attention(const unsigned short* __restrict__ qkv,   // [8192][3072] bf16
               const unsigned short* __restrict__ vt,    // [64][64][2048] bf16
               unsigned short* __restrict__ outb) {      // [8192][1024] bf16
    __shared__ unsigned short smem[4 * 64 * 72];
    const int tid = threadIdx.x;
    const int lane = tid & 63;
    const int wave = tid >> 6;
    const int l31 = lane & 31;
    const int half = lane >> 5;
    const int bh = blockIdx.x;
    const int b = bh >> 4;
    const int h = bh & 15;
    const int srow0 = tid >> 3;
    const int sch  = (tid & 7) * 8;

    const int qt = 15 - (int)blockIdx.y;
    const int qs = qt * 128 + wave * 32 + l31;
    const size_t qgrow = (size_t)b * SEQ + qs;

    bf16x8 qf[4];
    #pragma unroll
    for (int dt = 0; dt < 4; dt++)
        qf[dt] = *(const bf16x8*)&qkv[qgrow * 3072 + h * 64 + dt * 16 + half * 8];

    f32x16 o[2] = {};
    float m_prev = -1e30f, lsum = 0.f;

    const int nkb = 2 * qt + 2;
    const int qmax_w = qt * 128 + wave * 32 + 31;

    uint4 kreg[2], vreg[2];
    #pragma unroll
    for (int i = 0; i < 2; i++) {
        int row = srow0 + 32 * i;
        kreg[i] = *(const uint4*)&qkv[(size_t)(b * SEQ + row) * 3072 + EMB + h * 64 + sch];
        vreg[i] = *(const uint4*)&vt[(size_t)(bh * 64 + row) * SEQ + sch];
    }

    for (int kb = 0; kb < nkb; kb++) {
        unsigned short* Ks = smem + (kb & 1) * 2 * 64 * 72;
        unsigned short* Vs = Ks + 64 * 72;
        #pragma unroll
        for (int i = 0; i < 2; i++) {
            int row = srow0 + 32 * i;
            *(uint4*)&Ks[row * 72 + sch] = kreg[i];
            *(uint4*)&Vs[row * 72 + sch] = vreg[i];
        }
        if (kb + 1 < nkb) {
            #pragma unroll
            for (int i = 0; i < 2; i++) {
                int row = srow0 + 32 * i;
                kreg[i] = *(const uint4*)&qkv[(size_t)(b * SEQ + (kb + 1) * 64 + row) * 3072 + EMB + h * 64 + sch];
                vreg[i] = *(const uint4*)&vt[(size_t)(bh * 64 + row) * SEQ + (kb + 1) * 64 + sch];
            }
        }
        __syncthreads();

        if (kb * 64 > qmax_w) continue;

        // S^T = K Q^T : 2 c-tiles x 32 q
        f32x16 st[2] = {};
        #pragma unroll
        for (int dt = 0; dt < 4; dt++) {
            #pragma unroll
            for (int ct = 0; ct < 2; ct++) {
                bf16x8 kf = *(const bf16x8*)&Ks[(ct * 32 + l31) * 72 + dt * 16 + half * 8];
                st[ct] = __builtin_amdgcn_mfma_f32_32x32x16_bf16(kf, qf[dt], st[ct], 0, 0, 0);
            }
        }

        if (kb * 64 + 63 > qt * 128 + wave * 32) {
            #pragma unroll
            for (int ct = 0; ct < 2; ct++)
                #pragma unroll
                for (int r = 0; r < 16; r++) {
                    int cg = kb * 64 + ct * 32 + (r & 3) + 8 * (r >> 2) + 4 * half;
                    if (cg > qs) st[ct][r] = -1e9f;
                }
        }

        // online softmax: tree reductions + one cross-half shfl
        float tm[8];
        #pragma unroll
        for (int r = 0; r < 8; r++)
            tm[r] = fmaxf(fmaxf(st[0][r], st[1][r]), fmaxf(st[0][r + 8], st[1][r + 8]));
        #pragma unroll
        for (int s = 4; s > 0; s >>= 1)
            #pragma unroll
            for (int r = 0; r < s; r++) tm[r] = fmaxf(tm[r], tm[r + s]);
        float mx = fmaxf(tm[0], __shfl_xor(tm[0], 32, 64));
        float m_new = fmaxf(m_prev, mx);
        float alpha = exp2f((m_prev - m_new) * ATT_SCALE);
        float nmc = -m_new * ATT_SCALE;
        #pragma unroll
        for (int r = 0; r < 16; r++) {
            st[0][r] = exp2f(__builtin_fmaf(st[0][r], ATT_SCALE, nmc));
            st[1][r] = exp2f(__builtin_fmaf(st[1][r], ATT_SCALE, nmc));
        }
        float ts[8];
        #pragma unroll
        for (int r = 0; r < 8; r++)
            ts[r] = (st[0][r] + st[1][r]) + (st[0][r + 8] + st[1][r + 8]);
        #pragma unroll
        for (int s = 4; s > 0; s >>= 1)
            #pragma unroll
            for (int r = 0; r < s; r++) ts[r] += ts[r + s];
        float sum = ts[0] + __shfl_xor(ts[0], 32, 64);
        lsum = lsum * alpha + sum;
        m_prev = m_new;
        #pragma unroll
        for (int r = 0; r < 16; r++) { o[0][r] *= alpha; o[1][r] *= alpha; }

        // pack P to bf16 pairs
        unsigned int pk[2][8];
        #pragma unroll
        for (int t = 0; t < 2; t++)
            #pragma unroll
            for (int i = 0; i < 8; i++) {
                __hip_bfloat162 pb = __float22bfloat162_rn(float2{st[t][2 * i], st[t][2 * i + 1]});
                union { __hip_bfloat162 b; unsigned int u; } cv; cv.b = pb;
                pk[t][i] = cv.u;
            }

        // P^T B-frags via half-wave exchange; O^T += V^T P^T
        #pragma unroll
        for (int kt = 0; kt < 4; kt++) {
            const int t = kt >> 1, e = kt & 1;
            unsigned int own0 = half ? pk[t][4 * e + 2] : pk[t][4 * e + 0];
            unsigned int own1 = half ? pk[t][4 * e + 3] : pk[t][4 * e + 1];
            unsigned int snd0 = half ? pk[t][4 * e + 0] : pk[t][4 * e + 2];
            unsigned int snd1 = half ? pk[t][4 * e + 1] : pk[t][4 * e + 3];
            unsigned int rcv0 = (unsigned int)__shfl_xor((int)snd0, 32, 64);
            unsigned int rcv1 = (unsigned int)__shfl_xor((int)snd1, 32, 64);
            union { uint4 u; bf16x8 v; } pf;
            pf.u.x = half ? rcv0 : own0;
            pf.u.y = half ? rcv1 : own1;
            pf.u.z = half ? own0 : rcv0;
            pf.u.w = half ? own1 : rcv1;
            #pragma unroll
            for (int dt = 0; dt < 2; dt++) {
                bf16x8 vf = *(const bf16x8*)&Vs[(dt * 32 + l31) * 72 + kt * 16 + half * 8];
                o[dt] = __builtin_amdgcn_mfma_f32_32x32x16_bf16(vf, pf.v, o[dt], 0, 0, 0);
            }
        }
    }

    // epilogue: O^T -> LDS [q][d] -> coalesced bf16 store
    __syncthreads();
    float inv = 1.0f / lsum;
    #pragma unroll
    for (int dt = 0; dt < 2; dt++)
        #pragma unroll
        for (int r = 0; r < 16; r++) {
            int d = dt * 32 + (r & 3) + 8 * (r >> 2) + 4 * half;
            smem[(wave * 32 + l31) * 72 + d] = f2bf(o[dt][r] * inv);
        }
    __syncthreads();
    #pragma unroll
    for (int i = 0; i < 4; i++) {
        int c = tid + 256 * i;
        int row = c >> 3;
        int ch = (c & 7) * 8;
        uint4 v = *(const uint4*)&smem[row * 72 + ch];
        *(uint4*)&outb[(size_t)(b * SEQ + qt * 128 + row) * EMB + h * 64 + ch] = v;
    }
}

extern "C" void kernel_launch(void* const* d_in, const int* in_sizes, int n_in,
                              void* d_out, int out_size, void* d_ws, size_t ws_size,
                              hipStream_t stream) {
    const float* X     = (const float*)d_in[0];
    const float* Wqkv  = (const float*)d_in[1];
    const float* bqkv  = (const float*)d_in[2];
    const float* Wproj = (const float*)d_in[3];
    const float* bproj = (const float*)d_in[4];
    float* out = (float*)d_out;

    char* ws = (char*)d_ws;
    unsigned short* Xb     = (unsigned short*)(ws);                // 16,777,216 B
    unsigned short* WqkvT  = (unsigned short*)(ws + 16777216);     //  6,291,456 B
    unsigned short* WprojT = (unsigned short*)(ws + 23068672);     //  2,097,152 B
    unsigned short* qkvb   = (unsigned short*)(ws + 25165824);     // 50,331,648 B
    unsigned short* Vt     = (unsigned short*)(ws + 75497472);     // 16,777,216 B
    unsigned short* attnb  = (unsigned short*)(ws + 92274688);     // 16,777,216 B

    cvt_bf16<<<2048, 256, 0, stream>>>((const float4*)X, (ushort4*)Xb, (4 * 2048 * 1024) / 4);
    transpose_cvt<<<dim3(3072 / 32, 1024 / 32), 256, 0, stream>>>(Wqkv, WqkvT, 1024, 3072);
    transpose_cvt<<<dim3(1024 / 32, 1024 / 32), 256, 0, stream>>>(Wproj, WprojT, 1024, 1024);
    // qkv bf16 = X @ Wqkv + b ; V region written transposed to Vt. NPER = 24/8 = 3
    gemm_bf16<true, true, 3><<<(3072 / BN) * (8192 / BM), 256, 0, stream>>>(
        Xb, WqkvT, bqkv, qkvb, Vt, 8192, 3072, 1024);
    attention<<<dim3(64, 16), 256, 0, stream>>>(qkvb, Vt, attnb);
    // out fp32 = attn @ Wproj + b. NPER = 8/8 = 1
    gemm_bf16<false, false, 1><<<(1024 / BN) * (8192 / BM), 256, 0, stream>>>(
        attnb, WprojT, bproj, out, nullptr, 8192, 1024, 1024);
}